// Round 1
// baseline (1403.724 us; speedup 1.0000x reference)
//
#include <hip/hip_runtime.h>

// FrameOTAMDistanceNetwork: per (s,b): 8x8 cosine matrix between 8 support
// frames and 8 target frames (each 2048 fp32), then OTAM soft-DP both ways.
// Memory-bound: 436 MB compulsory reads -> ~70us floor at 6.3 TB/s.
//
// V2 structure: one block per (b, half-of-s). tv[b] staged ONCE per block,
// v-norms computed ONCE, then 12-13 s values processed two-at-a-time with
// register double-buffered sv prefetch. s-pair tiling halves LDS v-read
// traffic; one barrier per pair (parity-slotted sdot); DP tail rotates
// across waves.

constexpr int kNF   = 8;
constexpr int kFLEN = 2048;   // DF / NFRAMES
constexpr int kSeq  = 25;
constexpr int kBS   = 256;
constexpr int kDF   = 16384;
constexpr float kLam    = 0.1f;
constexpr float kInvLam = 10.0f;

__global__ __launch_bounds__(256, 2) void otam_kernel(
    const float* __restrict__ sv,   // [Seq, BS, DF]
    const float* __restrict__ tv,   // [BS, DF]
    float* __restrict__ out)        // [Seq, BS]
{
    __shared__ float V[kDF];                    // 64 KB: target frames for this b
    __shared__ float sdot[2][2][kNF][kNF];      // [pair parity][s-sub][i][j]
    __shared__ float rsnu[2][2][kNF];           // rsqrt(|u_i|^2), per parity/sub
    __shared__ float rnv[kNF];                  // rsqrt(|v_j|^2), once per block

    const int bid  = blockIdx.x;
    const int b    = bid >> 1;      // blocks 2b,2b+1 share tv[b]
    const int half = bid & 1;
    const int t    = threadIdx.x;
    const int g    = t >> 5;        // group 0..7: owns support frame g
    const int l    = t & 31;        // lane within group
    const int lane = t & 63;        // lane within wave

    const int sbeg   = half ? 12 : 0;
    const int scnt   = half ? 13 : 12;
    const int npairs = (scnt + 1) >> 1;   // 6 or 7 (last pair of half1 is a dup)

    // ---- stage tv[b] into LDS (issue these global loads FIRST so the
    //      ds_writes only wait on them, not on the sv prefetch below) ----
    {
        const float4* tv4 = (const float4*)(tv + (size_t)b * kDF);
        float4* V4 = (float4*)V;
        #pragma unroll
        for (int it = 0; it < 16; ++it)
            V4[it * 256 + t] = tv4[it * 256 + t];
    }

    // ---- prefetch first s-pair into registers (128 VGPR, double-buffered) ----
    float4 u0[16], u1[16];
    {
        const float4* p0 = (const float4*)(sv + ((size_t)(sbeg + 0) * kBS + b) * kDF + (size_t)g * kFLEN);
        const float4* p1 = (const float4*)(sv + ((size_t)(sbeg + 1) * kBS + b) * kDF + (size_t)g * kFLEN);
        #pragma unroll
        for (int c = 0; c < 16; ++c) { u0[c] = p0[c * 32 + l]; u1[c] = p1[c * 32 + l]; }
    }
    __syncthreads();

    // ---- v norms: once per block (was recomputed 25x per b before) ----
    {
        float v2 = 0.f;
        const float4* Vg = (const float4*)(V + g * kFLEN);
        #pragma unroll
        for (int c = 0; c < 16; ++c) {
            float4 v = Vg[c * 32 + l];
            v2 = fmaf(v.x, v.x, fmaf(v.y, v.y, fmaf(v.z, v.z, fmaf(v.w, v.w, v2))));
        }
        #pragma unroll
        for (int m = 16; m >= 1; m >>= 1) v2 += __shfl_xor(v2, m, 64);
        if (l == 0) rnv[g] = rsqrtf(v2);
        // read only by DP lanes, first after pair-0's barrier -> ordered
    }

    for (int k = 0; k < npairs; ++k) {
        const int  s0     = sbeg + 2 * k;
        const bool valid1 = (2 * k + 1) < scnt;
        const int  slot   = k & 1;

        // ---- dots: group g's two support frames (s0,s1) vs all 8 target
        //      frames. Each LDS v-read now feeds 2 dot chains (halved LDS). ----
        float dot0[kNF] = {}, dot1[kNF] = {};
        float n0 = 0.f, n1 = 0.f;
        #pragma unroll
        for (int c = 0; c < 16; ++c) {
            float4 a = u0[c], e2 = u1[c];
            n0 = fmaf(a.x, a.x, fmaf(a.y, a.y, fmaf(a.z, a.z, fmaf(a.w, a.w, n0))));
            n1 = fmaf(e2.x, e2.x, fmaf(e2.y, e2.y, fmaf(e2.z, e2.z, fmaf(e2.w, e2.w, n1))));
            #pragma unroll
            for (int j = 0; j < kNF; ++j) {
                // both halves of the wave read identical V addresses -> broadcast
                float4 v = ((const float4*)(V + j * kFLEN))[c * 32 + l];
                dot0[j] = fmaf(a.x, v.x, fmaf(a.y, v.y, fmaf(a.z, v.z, fmaf(a.w, v.w, dot0[j]))));
                dot1[j] = fmaf(e2.x, v.x, fmaf(e2.y, v.y, fmaf(e2.z, v.z, fmaf(e2.w, v.w, dot1[j]))));
            }
        }

        // ---- issue next pair's sv loads NOW: latency hides under the
        //      reduce + DP + next FMA ramp (no barrier between here and use) ----
        if (k + 1 < npairs) {
            const int ns0 = s0 + 2;
            const int ns1 = min(ns0 + 1, sbeg + scnt - 1);   // clamp dup for odd scnt
            const float4* p0 = (const float4*)(sv + ((size_t)ns0 * kBS + b) * kDF + (size_t)g * kFLEN);
            const float4* p1 = (const float4*)(sv + ((size_t)ns1 * kBS + b) * kDF + (size_t)g * kFLEN);
            #pragma unroll
            for (int c = 0; c < 16; ++c) { u0[c] = p0[c * 32 + l]; u1[c] = p1[c * 32 + l]; }
        }

        // ---- reduce 18 values across the 32-lane group (xor <=16 stays in-half) ----
        #pragma unroll
        for (int m = 16; m >= 1; m >>= 1) {
            n0 += __shfl_xor(n0, m, 64);
            n1 += __shfl_xor(n1, m, 64);
            #pragma unroll
            for (int j = 0; j < kNF; ++j) {
                dot0[j] += __shfl_xor(dot0[j], m, 64);
                dot1[j] += __shfl_xor(dot1[j], m, 64);
            }
        }
        if (l == 0) {
            rsnu[slot][0][g] = rsqrtf(n0);
            rsnu[slot][1][g] = rsqrtf(n1);
            #pragma unroll
            for (int j = 0; j < kNF; ++j) {
                sdot[slot][0][g][j] = dot0[j];
                sdot[slot][1][g][j] = dot1[j];
            }
        }
        __syncthreads();   // the ONLY barrier per pair (slot parity covers reuse)

        // ---- two DPs x two s on 32 lanes of wave (k&3): lanes 0-7 dp(D),
        //      8-15 dp(D^T) for s0; 16-31 same for s1. Normalization fused. ----
        if ((t >> 6) == (k & 3) && lane < 32) {
            const int  sub = lane >> 4;
            const int  idx = lane & 15;
            const int  r   = idx & 7;
            const bool xp  = idx >= 8;
            const float (*M)[kNF] = sdot[slot][sub];
            const float* ru = rsnu[slot][sub];

            auto Dm = [&](int rr, int ii) -> float {
                return xp ? M[ii][rr] * ru[ii] * rnv[rr]
                          : M[rr][ii] * ru[rr] * rnv[ii];
            };

            float prev = Dm(r, 0);
            #pragma unroll
            for (int i = 1; i < kNF; ++i) {
                float up = __shfl_up(prev, 1, 64);  // prev[r-1]; unused when r==0
                float d  = Dm(r, i);
                float mx = fmaxf(up, prev);
                float mn = fminf(up, prev);
                float lse = mx + kLam * log1pf(expf((mn - mx) * kInvLam));
                prev = (r == 0) ? (prev + d) : (lse + d);
            }
            // lam*logsumexp over the 8 rows (xor 4,2,1 stays in 8-lane group)
            float mx = prev;
            #pragma unroll
            for (int m = 4; m >= 1; m >>= 1) mx = fmaxf(mx, __shfl_xor(mx, m, 64));
            float e = expf((prev - mx) * kInvLam);
            #pragma unroll
            for (int m = 4; m >= 1; m >>= 1) e += __shfl_xor(e, m, 64);
            float res = mx + kLam * logf(e);

            float resT = __shfl(res, lane + 8, 64);  // pair dp1 lane with dp2 lane
            if (idx == 0 && (sub == 0 || valid1))
                out[(size_t)(s0 + sub) * kBS + b] = 0.5f * (res + resT);
        }
    }
}

extern "C" void kernel_launch(void* const* d_in, const int* in_sizes, int n_in,
                              void* d_out, int out_size, void* d_ws, size_t ws_size,
                              hipStream_t stream) {
    const float* sv = (const float*)d_in[0];
    const float* tv = (const float*)d_in[1];
    float* out = (float*)d_out;
    otam_kernel<<<dim3(2 * kBS), dim3(256), 0, stream>>>(sv, tv, out);
}